// Round 1
// baseline (169.426 us; speedup 1.0000x reference)
//
#include <hip/hip_runtime.h>
#include <math.h>

typedef __attribute__((ext_vector_type(8))) short short8;
typedef __attribute__((ext_vector_type(4))) float f32x4;
typedef __attribute__((ext_vector_type(4))) int i32x4;

#define DEV static __device__ __forceinline__

DEV unsigned short f2b(float f){            // fp32 -> bf16 (RNE)
  union{float f; unsigned u;} x; x.f = f;
  unsigned r = (x.u + 0x7fffu + ((x.u>>16)&1u))>>16;
  return (unsigned short)r;
}

#define MFMA(a,b,c) __builtin_amdgcn_mfma_f32_16x16x32_bf16((a),(b),(c),0,0,0)

// ---------------------------------------------------------------------------
// kprep: convert all weight matrices to bf16 in MFMA B-fragment order:
//   dst[((kc*NT+nt)*64 + lane)*8 + j] = W[kc*32 + (lane>>4)*8 + j][nt*16 + (lane&15)]
// so a B-fragment is one coalesced global dwordx4 per lane.
// ---------------------------------------------------------------------------
__global__ __launch_bounds__(256) void kprep(
    const float* __restrict__ inW, const float* __restrict__ Wq,
    const float* __restrict__ Wk,  const float* __restrict__ Wv,
    const float* __restrict__ m1,  const float* __restrict__ m2,
    const float* __restrict__ p1,  const float* __restrict__ p2,
    const float* __restrict__ p3,  const float* __restrict__ p4,
    unsigned short* __restrict__ wsw)
{
  int id = blockIdx.x*256 + threadIdx.x;
  const float* src; int KC, NT, base;
  if      (id < 49152){ src=inW; KC=24; NT=4; base=0; }
  else if (id < 67584){ int r=id-49152; int slab=r>>11; int h=slab/3, m=slab-h*3;
                        src = (m==0?Wq:(m==1?Wk:Wv)) + h*2048; KC=2; NT=2;
                        base = 49152 + slab*2048; }
  else if (id < 73728){ src=m1; KC=3; NT=4; base=67584; }
  else if (id < 77824){ src=m2; KC=2; NT=4; base=73728; }
  else if (id < 81920){ src=p1; KC=2; NT=4; base=77824; }
  else if (id < 86016){ src=p2; KC=2; NT=4; base=81920; }
  else if (id < 90112){ src=p3; KC=2; NT=4; base=86016; }
  else if (id < 94208){ src=p4; KC=2; NT=4; base=90112; }
  else return;
  (void)KC;
  int o = id - base;
  int j = o&7, l = (o>>3)&63, rest = o>>9;
  int nt = rest % NT, kc = rest / NT;
  int k = kc*32 + ((l>>4)<<3) + j;
  int n = nt*16 + (l&15);
  wsw[id] = f2b(src[k*(NT*16) + n]);
}

// ---------------------------------------------------------------------------
// k1: patchify + LN(768) + GEMM(768->64, MFMA) + bias + LN(64) -> xskip
// block = (b, p0): the 16 patches s = p0*16 + p1. Patch gather is coalesced:
// t[b, p0*16+p1, c*256+i*16+j] = x[b, c, i*16+p0, j*16+p1], thread w reads col w.
// ---------------------------------------------------------------------------
__global__ __launch_bounds__(256) void k1_patch(
    const float* __restrict__ x,
    const float* __restrict__ ln1s, const float* __restrict__ ln1b,
    const unsigned short* __restrict__ wsw, const float* __restrict__ inb,
    const float* __restrict__ ln2s, const float* __restrict__ ln2b,
    float* __restrict__ xskip)
{
  __shared__ unsigned short Tf[24*64*8];   // A-frags, frag-order (conflict-free b128)
  __shared__ float Cbuf[16][68];
  __shared__ float wstat[4][16][2];
  const int tid = threadIdx.x;
  const int lane = tid & 63, wv = tid >> 6;
  const int p1 = tid & 15, jj = tid >> 4;
  const int bp = blockIdx.x, b = bp >> 4, p0 = bp & 15;

  const float* xb = x + (size_t)b * (3*256*256);
  float rv[48]; float sum=0.f, ssq=0.f;
#pragma unroll
  for(int rr=0; rr<48; ++rr){
    int c = rr >> 4, i = rr & 15;
    float v = xb[(c*256 + i*16 + p0)*256 + tid];
    rv[rr] = v; sum += v; ssq += v*v;
  }
  sum += __shfl_xor(sum, 16); sum += __shfl_xor(sum, 32);
  ssq += __shfl_xor(ssq, 16); ssq += __shfl_xor(ssq, 32);
  if(lane < 16){ wstat[wv][lane][0] = sum; wstat[wv][lane][1] = ssq; }
  __syncthreads();
  float ts = wstat[0][p1][0] + wstat[1][p1][0] + wstat[2][p1][0] + wstat[3][p1][0];
  float tq = wstat[0][p1][1] + wstat[1][p1][1] + wstat[2][p1][1] + wstat[3][p1][1];
  float mean = ts * (1.f/768.f);
  float var  = tq * (1.f/768.f) - mean*mean;
  float rstd = rsqrtf(var + 1e-5f);
#pragma unroll
  for(int rr=0; rr<48; ++rr){
    int c = rr >> 4, i = rr & 15;
    int d = c*256 + i*16 + jj;
    float xv = (rv[rr]-mean)*rstd*ln1s[d] + ln1b[d];
    int g = (((i&1)<<4) + jj) >> 3;     // = (d&31)>>3
    Tf[ (((d>>5)*64 + g*16 + p1)<<3) + (jj&7) ] = f2b(xv);
  }
  __syncthreads();

  f32x4 acc = {0.f,0.f,0.f,0.f};
  const short8* wf = (const short8*)wsw;  // in_W frags: (kc*4+nt)*64+lane
#pragma unroll
  for(int kc=0; kc<24; ++kc){
    short8 a  = *(const short8*)&Tf[(kc*64 + lane)*8];
    short8 bb = wf[(kc*4 + wv)*64 + lane];
    acc = MFMA(a, bb, acc);
  }
  const int c15 = lane & 15, rg = lane >> 4;
  float bias = inb[wv*16 + c15];
#pragma unroll
  for(int r=0; r<4; ++r) Cbuf[rg*4+r][wv*16+c15] = acc[r] + bias;
  __syncthreads();

  {  // LN over 64 cols: 16 threads per row, 4 cols each
    int row = tid >> 4, cq = (tid & 15) * 4;
    float v0=Cbuf[row][cq+0], v1=Cbuf[row][cq+1], v2=Cbuf[row][cq+2], v3=Cbuf[row][cq+3];
    float s = v0+v1+v2+v3;
    float q = v0*v0+v1*v1+v2*v2+v3*v3;
    s += __shfl_xor(s,1); s += __shfl_xor(s,2); s += __shfl_xor(s,4); s += __shfl_xor(s,8);
    q += __shfl_xor(q,1); q += __shfl_xor(q,2); q += __shfl_xor(q,4); q += __shfl_xor(q,8);
    float m2  = s*(1.f/64.f);
    float rs2 = rsqrtf(q*(1.f/64.f) - m2*m2 + 1e-5f);
    f32x4 o;
    o[0] = (v0-m2)*rs2*ln2s[cq+0] + ln2b[cq+0];
    o[1] = (v1-m2)*rs2*ln2s[cq+1] + ln2b[cq+1];
    o[2] = (v2-m2)*rs2*ln2s[cq+2] + ln2b[cq+2];
    o[3] = (v3-m2)*rs2*ln2s[cq+3] + ln2b[cq+3];
    *(f32x4*)&xskip[ ((size_t)(b*256 + p0*16 + row))*64 + cq ] = o;
  }
}

// ---------------------------------------------------------------------------
// k2a: per (b,h): per-row LN(x_skip) -> bf16 A-frags (per-wave LDS) -> q,k,v via
// MFMA. q,k stored row-major bf16 [h][b][s][32]; v stored transposed [h][b][e][256].
// ---------------------------------------------------------------------------
__global__ __launch_bounds__(256) void k2a_qkv(
    const float* __restrict__ xskip,
    const float* __restrict__ mss, const float* __restrict__ msb,
    const unsigned short* __restrict__ wsw,
    const float* __restrict__ bq, const float* __restrict__ bk, const float* __restrict__ bv,
    unsigned short* __restrict__ qg, unsigned short* __restrict__ kg,
    unsigned short* __restrict__ vg)
{
  __shared__ unsigned short xbuf[4][1024];       // per-wave xn frag buffer
  __shared__ unsigned short vstage[32][264];     // V^T staging
  const int tid = threadIdx.x, lane = tid&63, wv = tid>>6;
  const int c15 = lane&15, rg = lane>>4;
  const int id = blockIdx.x, b = id/3, h = id - b*3;
  const float lns = mss[h*64 + lane], lnb = msb[h*64 + lane];
  float bqe[2] = { bq[h*32 + c15], bq[h*32 + 16 + c15] };
  float bke[2] = { bk[h*32 + c15], bk[h*32 + 16 + c15] };
  float bve[2] = { bv[h*32 + c15], bv[h*32 + 16 + c15] };
  const float* xr = xskip + (size_t)b*256*64;
  const short8* wf = (const short8*)(wsw + 49152);
  unsigned short* xb = xbuf[wv];
  size_t qkbase = (size_t)(h*256 + b) * (256*32);

  for(int st = wv; st < 16; st += 4){
    for(int rl=0; rl<16; ++rl){
      float v = xr[(st*16 + rl)*64 + lane];
      float s = v, q = v*v;
      s += __shfl_xor(s,1); s += __shfl_xor(s,2); s += __shfl_xor(s,4);
      s += __shfl_xor(s,8); s += __shfl_xor(s,16); s += __shfl_xor(s,32);
      q += __shfl_xor(q,1); q += __shfl_xor(q,2); q += __shfl_xor(q,4);
      q += __shfl_xor(q,8); q += __shfl_xor(q,16); q += __shfl_xor(q,32);
      float mean = s*(1.f/64.f);
      float rstd = rsqrtf(q*(1.f/64.f) - mean*mean + 1e-5f);
      float xn = (v-mean)*rstd*lns + lnb;
      xb[ (((lane>>5)*64 + ((lane&31)>>3)*16 + rl)<<3) + (lane&7) ] = f2b(xn);
    }
    short8 a0 = *(const short8*)&xb[(0*64 + lane)*8];
    short8 a1 = *(const short8*)&xb[(1*64 + lane)*8];
#pragma unroll
    for(int mat=0; mat<3; ++mat){
      const short8* wm = wf + (h*3 + mat)*256;
#pragma unroll
      for(int et=0; et<2; ++et){
        f32x4 acc = {0.f,0.f,0.f,0.f};
        acc = MFMA(a0, wm[(0*2+et)*64 + lane], acc);
        acc = MFMA(a1, wm[(1*2+et)*64 + lane], acc);
        float be = (mat==0? bqe[et] : (mat==1? bke[et] : bve[et]));
#pragma unroll
        for(int r=0; r<4; ++r){
          int s = st*16 + rg*4 + r;
          float val = acc[r] + be;
          if(mat==0)      qg[qkbase + s*32 + et*16 + c15] = f2b(val);
          else if(mat==1) kg[qkbase + s*32 + et*16 + c15] = f2b(val);
          else            vstage[et*16 + c15][s] = f2b(val);
        }
      }
    }
  }
  __syncthreads();
  {  // coalesced V^T write-out
    int e = tid >> 3, sb = (tid & 7) * 32;
    size_t gb = ((size_t)(h*256 + b)*32 + e) * 256 + sb;
#pragma unroll
    for(int u=0; u<4; ++u)
      *(i32x4*)&vg[gb + u*8] = *(const i32x4*)&vstage[e][sb + u*8];
  }
}

// ---------------------------------------------------------------------------
// k2b: per (b,h): scores = QK^T (MFMA), in-register softmax, P -> per-wave LDS
// frag buffer, out = P@V (MFMA) -> cat (bf16, [b][s][h*32+e]).
// ---------------------------------------------------------------------------
__global__ __launch_bounds__(256) void k2b_attn(
    const unsigned short* __restrict__ qg, const unsigned short* __restrict__ kg,
    const unsigned short* __restrict__ vg, unsigned short* __restrict__ cat)
{
  __shared__ unsigned short pf[4][4096];
  const int tid = threadIdx.x, lane = tid&63, wv = tid>>6;
  const int c15 = lane&15, rg = lane>>4;
  const int id = blockIdx.x, b = id/3, h = id - b*3;
  const unsigned short* qb = qg + (size_t)(h*256+b)*(256*32);
  const unsigned short* kb = kg + (size_t)(h*256+b)*(256*32);
  const unsigned short* vb = vg + (size_t)(h*256+b)*(32*256);
  unsigned short* pw = pf[wv];
  const f32x4 z = {0.f,0.f,0.f,0.f};

  for(int st = wv; st < 16; st += 4){
    short8 aq = *(const short8*)&qb[(st*16 + c15)*32 + rg*8];
    f32x4 sc[16];
#pragma unroll
    for(int tt=0; tt<16; ++tt){
      short8 kf = *(const short8*)&kb[(tt*16 + c15)*32 + rg*8];
      sc[tt] = MFMA(aq, kf, z);
    }
    float mx[4], sm[4];
#pragma unroll
    for(int r=0; r<4; ++r){
      float m = sc[0][r];
#pragma unroll
      for(int tt=1; tt<16; ++tt) m = fmaxf(m, sc[tt][r]);
      m = fmaxf(m, __shfl_xor(m,1)); m = fmaxf(m, __shfl_xor(m,2));
      m = fmaxf(m, __shfl_xor(m,4)); m = fmaxf(m, __shfl_xor(m,8));
      mx[r] = m; sm[r] = 0.f;
    }
#pragma unroll
    for(int tt=0; tt<16; ++tt)
#pragma unroll
      for(int r=0; r<4; ++r){
        float e = __expf(sc[tt][r] - mx[r]);
        sc[tt][r] = e; sm[r] += e;
      }
#pragma unroll
    for(int r=0; r<4; ++r){
      float s = sm[r];
      s += __shfl_xor(s,1); s += __shfl_xor(s,2); s += __shfl_xor(s,4); s += __shfl_xor(s,8);
      sm[r] = 1.f / s;
    }
#pragma unroll
    for(int tt=0; tt<16; ++tt){
      int tb = tt*16 + c15;
      int slot = ((tb>>5)*64 + ((tb&31)>>3)*16)*8 + (tb&7);
#pragma unroll
      for(int r=0; r<4; ++r)
        pw[slot + (rg*4 + r)*8] = f2b(sc[tt][r] * sm[r]);
    }
    f32x4 o0 = z, o1 = z;
#pragma unroll
    for(int kc=0; kc<8; ++kc){
      short8 pa = *(const short8*)&pw[(kc*64 + lane)*8];
      short8 v0 = *(const short8*)&vb[(c15)*256 + kc*32 + rg*8];
      short8 v1 = *(const short8*)&vb[(16 + c15)*256 + kc*32 + rg*8];
      o0 = MFMA(pa, v0, o0);
      o1 = MFMA(pa, v1, o1);
    }
#pragma unroll
    for(int r=0; r<4; ++r){
      size_t co = (size_t)(b*256 + st*16 + rg*4 + r)*96 + h*32;
      cat[co + c15]      = f2b(o0[r]);
      cat[co + 16 + c15] = f2b(o1[r]);
    }
  }
}

// ---------------------------------------------------------------------------
// k3: x_skip += (cat @ W1 + b1) @ W2 + b2   (in place; block = 64 rows)
// ---------------------------------------------------------------------------
__global__ __launch_bounds__(256) void k3_mhp(
    const unsigned short* __restrict__ cat,
    const unsigned short* __restrict__ w1f, const float* __restrict__ b1,
    const unsigned short* __restrict__ w2f, const float* __restrict__ b2,
    float* __restrict__ xskip)
{
  __shared__ unsigned short catf[6144];
  __shared__ unsigned short h1f[4096];
  const int tid = threadIdx.x, lane = tid&63, wv = tid>>6;
  const int c15 = lane&15, rg = lane>>4;
  const int bid = blockIdx.x, b = bid>>2, sg = bid&3;
  const unsigned short* cb = cat + (size_t)(b*256 + sg*64)*96;
#pragma unroll
  for(int it=0; it<24; ++it){
    int flat = it*256 + tid;
    int row = flat/96, col = flat - row*96;
    catf[ ((((row>>4)*3 + (col>>5))*64 + ((col&31)>>3)*16 + (row&15))<<3) + (col&7) ] = cb[flat];
  }
  __syncthreads();
  const short8* w1 = (const short8*)w1f;
  const short8* w2 = (const short8*)w2f;
  const int kch = wv>>1, gw = (wv&1)*2 + (c15>>3), jw = c15&7;
  float bias1 = b1[wv*16 + c15];
#pragma unroll
  for(int st=0; st<4; ++st){
    f32x4 a = {0.f,0.f,0.f,0.f};
#pragma unroll
    for(int kc=0; kc<3; ++kc)
      a = MFMA(*(const short8*)&catf[((st*3+kc)*64+lane)*8], w1[(kc*4+wv)*64+lane], a);
#pragma unroll
    for(int r=0; r<4; ++r)
      h1f[ (((st*2+kch)*64 + gw*16 + rg*4 + r)<<3) + jw ] = f2b(a[r] + bias1);
  }
  __syncthreads();
  float bias2 = b2[wv*16 + c15];
#pragma unroll
  for(int st=0; st<4; ++st){
    f32x4 a = {0.f,0.f,0.f,0.f};
#pragma unroll
    for(int kc=0; kc<2; ++kc)
      a = MFMA(*(const short8*)&h1f[((st*2+kc)*64+lane)*8], w2[(kc*4+wv)*64+lane], a);
#pragma unroll
    for(int r=0; r<4; ++r){
      size_t off = (size_t)(b*256 + sg*64 + st*16 + rg*4 + r)*64 + wv*16 + c15;
      xskip[off] += a[r] + bias2;
    }
  }
}

// ---------------------------------------------------------------------------
// k4: m = LN(xs2); 4 GEMMs (gelu after #2); partial[bid] = sum((m+xs2)*out_W)
// ---------------------------------------------------------------------------
__global__ __launch_bounds__(256) void k4_mlp(
    const float* __restrict__ xskip,
    const float* __restrict__ mls, const float* __restrict__ mlb,
    const unsigned short* __restrict__ w1f, const float* __restrict__ b1,
    const unsigned short* __restrict__ w2f, const float* __restrict__ b2,
    const unsigned short* __restrict__ w3f, const float* __restrict__ b3,
    const unsigned short* __restrict__ w4f, const float* __restrict__ b4,
    const float* __restrict__ outw, float* __restrict__ part)
{
  __shared__ unsigned short fa[4096];
  __shared__ unsigned short fb[4096];
  __shared__ float red[4];
  const int tid = threadIdx.x, lane = tid&63, wv = tid>>6;
  const int c15 = lane&15, rg = lane>>4;
  const int bid = blockIdx.x, b = bid>>2, sg = bid&3;
  const float* xr = xskip + (size_t)(b*256 + sg*64)*64;
  const float lns = mls[lane], lnb = mlb[lane];
  for(int rl=0; rl<16; ++rl){
    int row = wv*16 + rl;
    float v = xr[row*64 + lane];
    float s = v, q = v*v;
    s += __shfl_xor(s,1); s += __shfl_xor(s,2); s += __shfl_xor(s,4);
    s += __shfl_xor(s,8); s += __shfl_xor(s,16); s += __shfl_xor(s,32);
    q += __shfl_xor(q,1); q += __shfl_xor(q,2); q += __shfl_xor(q,4);
    q += __shfl_xor(q,8); q += __shfl_xor(q,16); q += __shfl_xor(q,32);
    float mean = s*(1.f/64.f);
    float rstd = rsqrtf(q*(1.f/64.f) - mean*mean + 1e-5f);
    float xn = (v - mean)*rstd*lns + lnb;
    fa[ (((wv*2 + (lane>>5))*64 + ((lane&31)>>3)*16 + rl)<<3) + (lane&7) ] = f2b(xn);
  }
  __syncthreads();
  const short8* w1 = (const short8*)w1f;
  const short8* w2 = (const short8*)w2f;
  const short8* w3 = (const short8*)w3f;
  const short8* w4 = (const short8*)w4f;
  const int kch = wv>>1, gw = (wv&1)*2 + (c15>>3), jw = c15&7;
  {  // G1: fa -> fb
    float bb = b1[wv*16+c15];
#pragma unroll
    for(int st=0; st<4; ++st){
      f32x4 a = {0.f,0.f,0.f,0.f};
#pragma unroll
      for(int kc=0; kc<2; ++kc)
        a = MFMA(*(const short8*)&fa[((st*2+kc)*64+lane)*8], w1[(kc*4+wv)*64+lane], a);
#pragma unroll
      for(int r=0; r<4; ++r)
        fb[ (((st*2+kch)*64 + gw*16 + rg*4 + r)<<3) + jw ] = f2b(a[r] + bb);
    }
  }
  __syncthreads();
  {  // G2 + exact gelu: fb -> fa
    float bb = b2[wv*16+c15];
#pragma unroll
    for(int st=0; st<4; ++st){
      f32x4 a = {0.f,0.f,0.f,0.f};
#pragma unroll
      for(int kc=0; kc<2; ++kc)
        a = MFMA(*(const short8*)&fb[((st*2+kc)*64+lane)*8], w2[(kc*4+wv)*64+lane], a);
#pragma unroll
      for(int r=0; r<4; ++r){
        float v = a[r] + bb;
        v = 0.5f*v*(1.f + erff(v*0.70710678118654752440f));
        fa[ (((st*2+kch)*64 + gw*16 + rg*4 + r)<<3) + jw ] = f2b(v);
      }
    }
  }
  __syncthreads();
  {  // G3: fa -> fb
    float bb = b3[wv*16+c15];
#pragma unroll
    for(int st=0; st<4; ++st){
      f32x4 a = {0.f,0.f,0.f,0.f};
#pragma unroll
      for(int kc=0; kc<2; ++kc)
        a = MFMA(*(const short8*)&fa[((st*2+kc)*64+lane)*8], w3[(kc*4+wv)*64+lane], a);
#pragma unroll
      for(int r=0; r<4; ++r)
        fb[ (((st*2+kch)*64 + gw*16 + rg*4 + r)<<3) + jw ] = f2b(a[r] + bb);
    }
  }
  __syncthreads();
  {  // G4 + residual + out_W partial reduction
    float bb = b4[wv*16+c15];
    float partial = 0.f;
#pragma unroll
    for(int st=0; st<4; ++st){
      f32x4 a = {0.f,0.f,0.f,0.f};
#pragma unroll
      for(int kc=0; kc<2; ++kc)
        a = MFMA(*(const short8*)&fb[((st*2+kc)*64+lane)*8], w4[(kc*4+wv)*64+lane], a);
#pragma unroll
      for(int r=0; r<4; ++r){
        int row = st*16 + rg*4 + r;
        float v = a[r] + bb + xr[row*64 + wv*16 + c15];
        partial += v * outw[(sg*64 + row)*64 + wv*16 + c15];
      }
    }
    partial += __shfl_xor(partial,1); partial += __shfl_xor(partial,2);
    partial += __shfl_xor(partial,4); partial += __shfl_xor(partial,8);
    partial += __shfl_xor(partial,16); partial += __shfl_xor(partial,32);
    if(lane==0) red[wv] = partial;
    __syncthreads();
    if(tid==0) part[bid] = red[0]+red[1]+red[2]+red[3];
  }
}

__global__ void k5_out(const float* __restrict__ part, const float* __restrict__ outb,
                       float* __restrict__ out){
  int b = threadIdx.x;
  out[b] = part[b*4] + part[b*4+1] + part[b*4+2] + part[b*4+3] + outb[0];
}

// ---------------------------------------------------------------------------
extern "C" void kernel_launch(void* const* d_in, const int* in_sizes, int n_in,
                              void* d_out, int out_size, void* d_ws, size_t ws_size,
                              hipStream_t stream)
{
  const float* x    = (const float*)d_in[0];
  const float* ln1s = (const float*)d_in[1];
  const float* ln1b = (const float*)d_in[2];
  const float* inW  = (const float*)d_in[3];
  const float* inb  = (const float*)d_in[4];
  const float* ln2s = (const float*)d_in[5];
  const float* ln2b = (const float*)d_in[6];
  const float* mss  = (const float*)d_in[7];
  const float* msb  = (const float*)d_in[8];
  const float* Wq   = (const float*)d_in[9];
  const float* bq   = (const float*)d_in[10];
  const float* Wk   = (const float*)d_in[11];
  const float* bk   = (const float*)d_in[12];
  const float* Wv   = (const float*)d_in[13];
  const float* bv   = (const float*)d_in[14];
  const float* mhW1 = (const float*)d_in[15];
  const float* mhb1 = (const float*)d_in[16];
  const float* mhW2 = (const float*)d_in[17];
  const float* mhb2 = (const float*)d_in[18];
  const float* mls  = (const float*)d_in[19];
  const float* mlb  = (const float*)d_in[20];
  const float* mW1  = (const float*)d_in[21];
  const float* mb1  = (const float*)d_in[22];
  const float* mW2  = (const float*)d_in[23];
  const float* mb2  = (const float*)d_in[24];
  const float* mW3  = (const float*)d_in[25];
  const float* mb3  = (const float*)d_in[26];
  const float* mW4  = (const float*)d_in[27];
  const float* mb4  = (const float*)d_in[28];
  const float* outW = (const float*)d_in[29];
  const float* outb = (const float*)d_in[30];
  (void)in_sizes; (void)n_in; (void)out_size;

  // workspace layout (bytes)
  char* ws = (char*)d_ws;
  float*          xskip = (float*)         (ws + 0);          // 16,777,216 B
  unsigned short* cat   = (unsigned short*)(ws + 16777216);   // 12,582,912 B
  unsigned short* qg    = (unsigned short*)(ws + 29360128);   // 12,582,912 B
  unsigned short* kg    = (unsigned short*)(ws + 41943040);   // 12,582,912 B
  unsigned short* vg    = (unsigned short*)(ws + 54525952);   // 12,582,912 B
  unsigned short* wsw   = (unsigned short*)(ws + 67108864);   //    188,416 B
  float*          part  = (float*)         (ws + 67297280);   //      4,096 B
  if(ws_size < 67301376u) return;  // insufficient workspace — will fail validation visibly

  float* out = (float*)d_out;

  kprep<<<dim3(368), dim3(256), 0, stream>>>(inW, Wq, Wk, Wv, mhW1, mhW2, mW1, mW2, mW3, mW4, wsw);
  k1_patch<<<dim3(4096), dim3(256), 0, stream>>>(x, ln1s, ln1b, wsw, inb, ln2s, ln2b, xskip);
  k2a_qkv<<<dim3(768), dim3(256), 0, stream>>>(xskip, mss, msb, wsw, bq, bk, bv, qg, kg, vg);
  k2b_attn<<<dim3(768), dim3(256), 0, stream>>>(qg, kg, vg, cat);
  k3_mhp<<<dim3(1024), dim3(256), 0, stream>>>(cat, wsw + 67584, mhb1, wsw + 73728, mhb2, xskip);
  k4_mlp<<<dim3(1024), dim3(256), 0, stream>>>(xskip, mls, mlb,
      wsw + 77824, mb1, wsw + 81920, mb2, wsw + 86016, mb3, wsw + 90112, mb4, outW, part);
  k5_out<<<dim3(1), dim3(256), 0, stream>>>(part, outb, out);
}

// Round 3
// 115.216 us; speedup vs baseline: 1.4705x; 1.4705x over previous
//
#include <hip/hip_runtime.h>
#include <math.h>

typedef __attribute__((ext_vector_type(8))) short short8;
typedef __attribute__((ext_vector_type(4))) short short4v;
typedef __attribute__((ext_vector_type(4))) float f32x4;
typedef __attribute__((ext_vector_type(2))) float f32x2;

#define DEV static __device__ __forceinline__

DEV unsigned short f2b(float f){            // fp32 -> bf16 (RNE)
  union{float f; unsigned u;} x; x.f = f;
  unsigned r = (x.u + 0x7fffu + ((x.u>>16)&1u))>>16;
  return (unsigned short)r;
}

#define MFMA(a,b,c) __builtin_amdgcn_mfma_f32_16x16x32_bf16((a),(b),(c),0,0,0)

// ---------------------------------------------------------------------------
// kprep: weights -> bf16 MFMA B-frag order, with LN-affine folding:
//   qkv weights scaled by msa_ln_s; mlp_W1 scaled by mlp_ln_s.
// Also computes folded biases: qkvb[h][mat][e] = msa_ln_b@W + b;
//   mlpb1[n] = mlp_ln_b@mW1 + mb1.
// ---------------------------------------------------------------------------
__global__ __launch_bounds__(256) void kprep(
    const float* __restrict__ inW, const float* __restrict__ Wq,
    const float* __restrict__ Wk,  const float* __restrict__ Wv,
    const float* __restrict__ m1,  const float* __restrict__ m2,
    const float* __restrict__ p1,  const float* __restrict__ p2,
    const float* __restrict__ p3,  const float* __restrict__ p4,
    const float* __restrict__ mss, const float* __restrict__ mls,
    const float* __restrict__ msb,
    const float* __restrict__ bq,  const float* __restrict__ bk,
    const float* __restrict__ bv,
    const float* __restrict__ mlb, const float* __restrict__ mb1,
    unsigned short* __restrict__ wsw, float* __restrict__ qkvb,
    float* __restrict__ mlpb1)
{
  int id = blockIdx.x*256 + threadIdx.x;
  if(id < 94208){
    const float* src; int NT, base; int harg = -1, w1flag = 0;
    if      (id < 49152){ src=inW; NT=4; base=0; }
    else if (id < 67584){ int r=id-49152; int slab=r>>11; int h=slab/3, m=slab-h*3;
                          src=(m==0?Wq:(m==1?Wk:Wv))+h*2048; NT=2; base=49152+slab*2048; harg=h; }
    else if (id < 73728){ src=m1; NT=4; base=67584; }
    else if (id < 77824){ src=m2; NT=4; base=73728; }
    else if (id < 81920){ src=p1; NT=4; base=77824; w1flag=1; }
    else if (id < 86016){ src=p2; NT=4; base=81920; }
    else if (id < 90112){ src=p3; NT=4; base=86016; }
    else                { src=p4; NT=4; base=90112; }
    int o = id - base;
    int j = o&7, l = (o>>3)&63, rest = o>>9;
    int nt = rest % NT, kc = rest / NT;
    int k = kc*32 + ((l>>4)<<3) + j;
    int n = nt*16 + (l&15);
    float scale = 1.f;
    if(harg >= 0) scale = mss[harg*64 + k];
    if(w1flag)    scale = mls[k];
    wsw[id] = f2b(src[k*(NT*16) + n] * scale);
  } else if(id < 94496){
    int o = id - 94208;                     // 288: h*96 + m*32 + e
    int h = o/96, m = (o - h*96)/32, e = o&31;
    const float* W  = (m==0?Wq:(m==1?Wk:Wv)) + h*2048;
    const float* bb = (m==0?bq:(m==1?bk:bv));
    float s = 0.f;
    for(int l=0;l<64;++l) s += msb[h*64+l]*W[l*32+e];
    qkvb[o] = s + bb[h*32+e];
  } else if(id < 94560){
    int n = id - 94496;
    float s = 0.f;
    for(int l=0;l<64;++l) s += mlb[l]*p1[l*64+n];
    mlpb1[n] = s + mb1[n];
  }
}

// ---------------------------------------------------------------------------
// k1: patchify + LN(768) + GEMM(768->64, MFMA) + bias + LN(64) -> xskip,
//     plus per-row (mean, rstd) of xskip for the downstream (folded) LNs.
// ---------------------------------------------------------------------------
__global__ __launch_bounds__(256) void k1_patch(
    const float* __restrict__ x,
    const float* __restrict__ ln1s, const float* __restrict__ ln1b,
    const unsigned short* __restrict__ wsw, const float* __restrict__ inb,
    const float* __restrict__ ln2s, const float* __restrict__ ln2b,
    float* __restrict__ xskip, float* __restrict__ rowstats)
{
  __shared__ unsigned short Tf[24*64*8];
  __shared__ float Cbuf[16][68];
  __shared__ float wstat[4][16][2];
  const int tid = threadIdx.x;
  const int lane = tid & 63, wv = tid >> 6;
  const int p1 = tid & 15, jj = tid >> 4;
  const int bp = blockIdx.x, b = bp >> 4, p0 = bp & 15;

  const float* xb = x + (size_t)b * (3*256*256);
  float rv[48]; float sum=0.f, ssq=0.f;
#pragma unroll
  for(int rr=0; rr<48; ++rr){
    int c = rr >> 4, i = rr & 15;
    float v = xb[(c*256 + i*16 + p0)*256 + tid];
    rv[rr] = v; sum += v; ssq += v*v;
  }
  sum += __shfl_xor(sum, 16); sum += __shfl_xor(sum, 32);
  ssq += __shfl_xor(ssq, 16); ssq += __shfl_xor(ssq, 32);
  if(lane < 16){ wstat[wv][lane][0] = sum; wstat[wv][lane][1] = ssq; }
  __syncthreads();
  float ts = wstat[0][p1][0] + wstat[1][p1][0] + wstat[2][p1][0] + wstat[3][p1][0];
  float tq = wstat[0][p1][1] + wstat[1][p1][1] + wstat[2][p1][1] + wstat[3][p1][1];
  float mean = ts * (1.f/768.f);
  float var  = tq * (1.f/768.f) - mean*mean;
  float rstd = rsqrtf(var + 1e-5f);
#pragma unroll
  for(int rr=0; rr<48; ++rr){
    int c = rr >> 4, i = rr & 15;
    int d = c*256 + i*16 + jj;
    float xv = (rv[rr]-mean)*rstd*ln1s[d] + ln1b[d];
    int g = (((i&1)<<4) + jj) >> 3;
    Tf[ (((d>>5)*64 + g*16 + p1)<<3) + (jj&7) ] = f2b(xv);
  }
  __syncthreads();

  f32x4 acc = {0.f,0.f,0.f,0.f};
  const short8* wf = (const short8*)wsw;
#pragma unroll
  for(int kc=0; kc<24; ++kc){
    short8 a  = *(const short8*)&Tf[(kc*64 + lane)*8];
    short8 bb = wf[(kc*4 + wv)*64 + lane];
    acc = MFMA(a, bb, acc);
  }
  const int c15 = lane & 15, rg = lane >> 4;
  float bias = inb[wv*16 + c15];
#pragma unroll
  for(int r=0; r<4; ++r) Cbuf[rg*4+r][wv*16+c15] = acc[r] + bias;
  __syncthreads();

  {
    int row = tid >> 4, cq = (tid & 15) * 4;
    float v0=Cbuf[row][cq+0], v1=Cbuf[row][cq+1], v2=Cbuf[row][cq+2], v3=Cbuf[row][cq+3];
    float s = v0+v1+v2+v3;
    float q = v0*v0+v1*v1+v2*v2+v3*v3;
    s += __shfl_xor(s,1); s += __shfl_xor(s,2); s += __shfl_xor(s,4); s += __shfl_xor(s,8);
    q += __shfl_xor(q,1); q += __shfl_xor(q,2); q += __shfl_xor(q,4); q += __shfl_xor(q,8);
    float m2  = s*(1.f/64.f);
    float rs2 = rsqrtf(q*(1.f/64.f) - m2*m2 + 1e-5f);
    f32x4 o;
    o[0] = (v0-m2)*rs2*ln2s[cq+0] + ln2b[cq+0];
    o[1] = (v1-m2)*rs2*ln2s[cq+1] + ln2b[cq+1];
    o[2] = (v2-m2)*rs2*ln2s[cq+2] + ln2b[cq+2];
    o[3] = (v3-m2)*rs2*ln2s[cq+3] + ln2b[cq+3];
    int grow = b*256 + p0*16 + row;
    *(f32x4*)&xskip[ (size_t)grow*64 + cq ] = o;
    // per-row stats of xskip (for folded downstream LNs)
    float s2 = o[0]+o[1]+o[2]+o[3];
    float q2 = o[0]*o[0]+o[1]*o[1]+o[2]*o[2]+o[3]*o[3];
    s2 += __shfl_xor(s2,1); s2 += __shfl_xor(s2,2); s2 += __shfl_xor(s2,4); s2 += __shfl_xor(s2,8);
    q2 += __shfl_xor(q2,1); q2 += __shfl_xor(q2,2); q2 += __shfl_xor(q2,4); q2 += __shfl_xor(q2,8);
    if((tid & 15) == 0){
      float mm = s2*(1.f/64.f);
      float rr2 = rsqrtf(q2*(1.f/64.f) - mm*mm + 1e-5f);
      f32x2 st; st[0] = mm; st[1] = rr2;
      *(f32x2*)&rowstats[grow*2] = st;
    }
  }
}

// ---------------------------------------------------------------------------
// kA: fused attention per (b,h). z = (xskip-mean)*rstd -> LDS A-frags;
// QKV GEMMs (folded weights/biases) -> Q/K/V frag-order LDS; QK^T, in-register
// softmax, P -> per-wave frag buffer (reusing zfrag region), PV -> cat.
// LDS: [0,16384) z/P | [16384,24576) Q | [24576,32768) K | [32768,40960) V
// ---------------------------------------------------------------------------
__global__ __launch_bounds__(256) void kA_attn(
    const float* __restrict__ xskip, const float* __restrict__ rowstats,
    const unsigned short* __restrict__ wsw, const float* __restrict__ qkvb,
    unsigned short* __restrict__ cat)
{
  __shared__ unsigned short sh[40960];   // 80 KB
  const int tid = threadIdx.x, lane = tid&63, wv = tid>>6;
  const int c15 = lane&15, rg = lane>>4;
  const int id = blockIdx.x, b = id/3, h = id - b*3;
  const float* xr = xskip + (size_t)b*16384;

  {  // z-prep: coalesced f32x4 loads, frag-order bf16 writes
    int rbase = tid>>4, col = (tid&15)*4;
#pragma unroll
    for(int it=0; it<16; ++it){
      int row = it*16 + rbase;
      f32x4 v = *(const f32x4*)&xr[row*64 + col];
      f32x2 st = *(const f32x2*)&rowstats[(b*256+row)*2];
      short4v z;
      z[0]=(short)f2b((v[0]-st[0])*st[1]); z[1]=(short)f2b((v[1]-st[0])*st[1]);
      z[2]=(short)f2b((v[2]-st[0])*st[1]); z[3]=(short)f2b((v[3]-st[0])*st[1]);
      int zi = ((it*2 + (col>>5))*64 + ((col&31)>>3)*16 + rbase)*8 + (col&7);
      *(short4v*)&sh[zi] = z;
    }
  }
  __syncthreads();

  {  // QKV GEMMs
    const short8* zf8 = (const short8*)sh;
    const short8* wf  = ((const short8*)(wsw + 49152)) + h*3*256;
    float be[6];
#pragma unroll
    for(int i=0;i<6;++i) be[i] = qkvb[(h*3 + (i>>1))*32 + (i&1)*16 + c15];
    for(int st = wv; st < 16; st += 4){
      short8 a0 = zf8[(st*2+0)*64 + lane];
      short8 a1 = zf8[(st*2+1)*64 + lane];
#pragma unroll
      for(int mat=0; mat<3; ++mat){
#pragma unroll
        for(int et=0; et<2; ++et){
          f32x4 acc = {0.f,0.f,0.f,0.f};
          acc = MFMA(a0, wf[mat*256 + et*64 + lane], acc);
          acc = MFMA(a1, wf[mat*256 + (2+et)*64 + lane], acc);
          float bias = be[mat*2+et];
#pragma unroll
          for(int r=0;r<4;++r){
            int s15 = rg*4 + r;
            unsigned short val = f2b(acc[r] + bias);
            if(mat<2){
              int idx = (st*64 + (et*2 + (c15>>3))*16 + s15)*8 + (c15&7);
              sh[(mat==0?16384:24576) + idx] = val;
            } else {
              int s = st*16 + s15;
              int idx = (((s>>5)*2 + et)*64 + ((s&31)>>3)*16 + c15)*8 + (s&7);
              sh[32768 + idx] = val;
            }
          }
        }
      }
    }
  }
  __syncthreads();

  {  // attention
    unsigned short* pw = sh + wv*4096;     // reuse zfrag region (per-wave 8 KB)
    const short8* qf8 = (const short8*)(sh + 16384);
    const short8* kf8 = (const short8*)(sh + 24576);
    const short8* vf8 = (const short8*)(sh + 32768);
    const f32x4 z4 = {0.f,0.f,0.f,0.f};
    for(int st = wv; st < 16; st += 4){
      short8 aq = qf8[st*64 + lane];
      f32x4 sc[16];
#pragma unroll
      for(int tt=0; tt<16; ++tt) sc[tt] = MFMA(aq, kf8[tt*64 + lane], z4);
      float mx[4], sm[4];
#pragma unroll
      for(int r=0; r<4; ++r){
        float m = sc[0][r];
#pragma unroll
        for(int tt=1; tt<16; ++tt) m = fmaxf(m, sc[tt][r]);
        m = fmaxf(m, __shfl_xor(m,1)); m = fmaxf(m, __shfl_xor(m,2));
        m = fmaxf(m, __shfl_xor(m,4)); m = fmaxf(m, __shfl_xor(m,8));
        mx[r] = m; sm[r] = 0.f;
      }
#pragma unroll
      for(int tt=0; tt<16; ++tt)
#pragma unroll
        for(int r=0; r<4; ++r){
          float e = __expf(sc[tt][r] - mx[r]);
          sc[tt][r] = e; sm[r] += e;
        }
#pragma unroll
      for(int r=0; r<4; ++r){
        float s = sm[r];
        s += __shfl_xor(s,1); s += __shfl_xor(s,2); s += __shfl_xor(s,4); s += __shfl_xor(s,8);
        sm[r] = 1.f / s;
      }
#pragma unroll
      for(int tt=0; tt<16; ++tt){
        int tb = tt*16 + c15;
        int slot = ((tb>>5)*64 + ((tb&31)>>3)*16)*8 + (tb&7);
#pragma unroll
        for(int r=0; r<4; ++r)
          pw[slot + (rg*4 + r)*8] = f2b(sc[tt][r] * sm[r]);
      }
      f32x4 o0 = z4, o1 = z4;
#pragma unroll
      for(int kc=0; kc<8; ++kc){
        short8 pa = *(const short8*)&pw[(kc*64 + lane)*8];
        o0 = MFMA(pa, vf8[(kc*2+0)*64 + lane], o0);
        o1 = MFMA(pa, vf8[(kc*2+1)*64 + lane], o1);
      }
#pragma unroll
      for(int r=0; r<4; ++r){
        size_t co = (size_t)(b*256 + st*16 + rg*4 + r)*96 + h*32;
        cat[co + c15]      = f2b(o0[r]);
        cat[co + 16 + c15] = f2b(o1[r]);
      }
    }
  }
}

// ---------------------------------------------------------------------------
// kB: fused tail per (b, 64-row group): mhp 2-GEMM + residual (registers),
// in-kernel LN stats, mlp 4-GEMM chain (folded b1', exact gelu), residual,
// fused out_W partial dot -> part[bid].
// ---------------------------------------------------------------------------
__global__ __launch_bounds__(256) void kB_tail(
    const unsigned short* __restrict__ cat, const float* __restrict__ xskip,
    const unsigned short* __restrict__ w1f, const float* __restrict__ b1,
    const unsigned short* __restrict__ w2f, const float* __restrict__ b2,
    const unsigned short* __restrict__ p1f, const float* __restrict__ p1b,
    const unsigned short* __restrict__ p2f, const float* __restrict__ pb2,
    const unsigned short* __restrict__ p3f, const float* __restrict__ pb3,
    const unsigned short* __restrict__ p4f, const float* __restrict__ pb4,
    const float* __restrict__ outw, float* __restrict__ part)
{
  __shared__ unsigned short catf[6144];
  __shared__ unsigned short fa[4096];
  __shared__ unsigned short fb[4096];
  __shared__ float rstat[4][64][2];
  __shared__ float red[4];
  const int tid = threadIdx.x, lane = tid&63, wv = tid>>6;
  const int c15 = lane&15, rg = lane>>4;
  const int bid = blockIdx.x, b = bid>>2, sg = bid&3;
  const unsigned short* cb = cat + (size_t)(b*256 + sg*64)*96;
#pragma unroll
  for(int it=0; it<24; ++it){
    int flat = it*256 + tid;
    int row = flat/96, col = flat - row*96;
    catf[ ((((row>>4)*3 + (col>>5))*64 + ((col&31)>>3)*16 + (row&15))<<3) + (col&7) ] = cb[flat];
  }
  __syncthreads();
  const short8* w1 = (const short8*)w1f;
  const short8* w2 = (const short8*)w2f;
  const short8* q1 = (const short8*)p1f;
  const short8* q2 = (const short8*)p2f;
  const short8* q3 = (const short8*)p3f;
  const short8* q4 = (const short8*)p4f;
  const int kch = wv>>1, gw = (wv&1)*2 + (c15>>3), jw = c15&7;
  {  // mhp G1 -> fa
    float bb = b1[wv*16+c15];
#pragma unroll
    for(int st=0; st<4; ++st){
      f32x4 a = {0.f,0.f,0.f,0.f};
#pragma unroll
      for(int kc=0; kc<3; ++kc)
        a = MFMA(*(const short8*)&catf[((st*3+kc)*64+lane)*8], w1[(kc*4+wv)*64+lane], a);
#pragma unroll
      for(int r=0; r<4; ++r)
        fa[ (((st*2+kch)*64 + gw*16 + rg*4 + r)<<3) + jw ] = f2b(a[r] + bb);
    }
  }
  __syncthreads();
  // mhp G2 + residual -> xs2 (registers)
  f32x4 xs2[4];
  const float* xr = xskip + (size_t)(b*256 + sg*64)*64;
  {
    float bb = b2[wv*16+c15];
#pragma unroll
    for(int st=0; st<4; ++st){
      f32x4 a = {0.f,0.f,0.f,0.f};
#pragma unroll
      for(int kc=0; kc<2; ++kc)
        a = MFMA(*(const short8*)&fa[((st*2+kc)*64+lane)*8], w2[(kc*4+wv)*64+lane], a);
#pragma unroll
      for(int r=0; r<4; ++r)
        xs2[st][r] = a[r] + bb + xr[(st*16 + rg*4 + r)*64 + wv*16 + c15];
    }
  }
  // LN stats of xs2 rows
#pragma unroll
  for(int st=0; st<4; ++st)
#pragma unroll
    for(int r=0; r<4; ++r){
      float sv = xs2[st][r], qv = sv*sv;
      sv += __shfl_xor(sv,1); sv += __shfl_xor(sv,2); sv += __shfl_xor(sv,4); sv += __shfl_xor(sv,8);
      qv += __shfl_xor(qv,1); qv += __shfl_xor(qv,2); qv += __shfl_xor(qv,4); qv += __shfl_xor(qv,8);
      if(c15==0){ int row = st*16+rg*4+r; rstat[wv][row][0]=sv; rstat[wv][row][1]=qv; }
    }
  __syncthreads();
  // z2 -> fa (unscaled; scale folded into p1f/p1b)
#pragma unroll
  for(int st=0; st<4; ++st)
#pragma unroll
    for(int r=0; r<4; ++r){
      int row = st*16+rg*4+r;
      float tsu = rstat[0][row][0]+rstat[1][row][0]+rstat[2][row][0]+rstat[3][row][0];
      float tqu = rstat[0][row][1]+rstat[1][row][1]+rstat[2][row][1]+rstat[3][row][1];
      float mean = tsu*(1.f/64.f);
      float rstd = rsqrtf(tqu*(1.f/64.f) - mean*mean + 1e-5f);
      fa[ (((st*2+kch)*64 + gw*16 + (row&15))<<3) + jw ] = f2b((xs2[st][r]-mean)*rstd);
    }
  __syncthreads();
  {  // mlp G1 (folded) -> fb
    float bb = p1b[wv*16+c15];
#pragma unroll
    for(int st=0; st<4; ++st){
      f32x4 a = {0.f,0.f,0.f,0.f};
#pragma unroll
      for(int kc=0; kc<2; ++kc)
        a = MFMA(*(const short8*)&fa[((st*2+kc)*64+lane)*8], q1[(kc*4+wv)*64+lane], a);
#pragma unroll
      for(int r=0; r<4; ++r)
        fb[ (((st*2+kch)*64 + gw*16 + rg*4 + r)<<3) + jw ] = f2b(a[r] + bb);
    }
  }
  __syncthreads();
  {  // mlp G2 + exact gelu -> fa
    float bb = pb2[wv*16+c15];
#pragma unroll
    for(int st=0; st<4; ++st){
      f32x4 a = {0.f,0.f,0.f,0.f};
#pragma unroll
      for(int kc=0; kc<2; ++kc)
        a = MFMA(*(const short8*)&fb[((st*2+kc)*64+lane)*8], q2[(kc*4+wv)*64+lane], a);
#pragma unroll
      for(int r=0; r<4; ++r){
        float v = a[r] + bb;
        v = 0.5f*v*(1.f + erff(v*0.70710678118654752440f));
        fa[ (((st*2+kch)*64 + gw*16 + rg*4 + r)<<3) + jw ] = f2b(v);
      }
    }
  }
  __syncthreads();
  {  // mlp G3 -> fb
    float bb = pb3[wv*16+c15];
#pragma unroll
    for(int st=0; st<4; ++st){
      f32x4 a = {0.f,0.f,0.f,0.f};
#pragma unroll
      for(int kc=0; kc<2; ++kc)
        a = MFMA(*(const short8*)&fa[((st*2+kc)*64+lane)*8], q3[(kc*4+wv)*64+lane], a);
#pragma unroll
      for(int r=0; r<4; ++r)
        fb[ (((st*2+kch)*64 + gw*16 + rg*4 + r)<<3) + jw ] = f2b(a[r] + bb);
    }
  }
  __syncthreads();
  {  // mlp G4 + residual + out_W partial dot
    float bb = pb4[wv*16+c15];
    float partial = 0.f;
#pragma unroll
    for(int st=0; st<4; ++st){
      f32x4 a = {0.f,0.f,0.f,0.f};
#pragma unroll
      for(int kc=0; kc<2; ++kc)
        a = MFMA(*(const short8*)&fb[((st*2+kc)*64+lane)*8], q4[(kc*4+wv)*64+lane], a);
#pragma unroll
      for(int r=0; r<4; ++r){
        int row = st*16 + rg*4 + r;
        float v = a[r] + bb + xs2[st][r];
        partial += v * outw[(sg*64 + row)*64 + wv*16 + c15];
      }
    }
    partial += __shfl_xor(partial,1); partial += __shfl_xor(partial,2);
    partial += __shfl_xor(partial,4); partial += __shfl_xor(partial,8);
    partial += __shfl_xor(partial,16); partial += __shfl_xor(partial,32);
    if(lane==0) red[wv] = partial;
    __syncthreads();
    if(tid==0) part[bid] = red[0]+red[1]+red[2]+red[3];
  }
}

__global__ void k5_out(const float* __restrict__ part, const float* __restrict__ outb,
                       float* __restrict__ out){
  int b = threadIdx.x;
  out[b] = part[b*4] + part[b*4+1] + part[b*4+2] + part[b*4+3] + outb[0];
}

// ---------------------------------------------------------------------------
extern "C" void kernel_launch(void* const* d_in, const int* in_sizes, int n_in,
                              void* d_out, int out_size, void* d_ws, size_t ws_size,
                              hipStream_t stream)
{
  const float* x    = (const float*)d_in[0];
  const float* ln1s = (const float*)d_in[1];
  const float* ln1b = (const float*)d_in[2];
  const float* inW  = (const float*)d_in[3];
  const float* inb  = (const float*)d_in[4];
  const float* ln2s = (const float*)d_in[5];
  const float* ln2b = (const float*)d_in[6];
  const float* mss  = (const float*)d_in[7];
  const float* msb  = (const float*)d_in[8];
  const float* Wq   = (const float*)d_in[9];
  const float* bq   = (const float*)d_in[10];
  const float* Wk   = (const float*)d_in[11];
  const float* bk   = (const float*)d_in[12];
  const float* Wv   = (const float*)d_in[13];
  const float* bv   = (const float*)d_in[14];
  const float* mhW1 = (const float*)d_in[15];
  const float* mhb1 = (const float*)d_in[16];
  const float* mhW2 = (const float*)d_in[17];
  const float* mhb2 = (const float*)d_in[18];
  const float* mls  = (const float*)d_in[19];
  const float* mlb  = (const float*)d_in[20];
  const float* mW1  = (const float*)d_in[21];
  const float* mb1  = (const float*)d_in[22];
  const float* mW2  = (const float*)d_in[23];
  const float* mb2  = (const float*)d_in[24];
  const float* mW3  = (const float*)d_in[25];
  const float* mb3  = (const float*)d_in[26];
  const float* mW4  = (const float*)d_in[27];
  const float* mb4  = (const float*)d_in[28];
  const float* outW = (const float*)d_in[29];
  const float* outb = (const float*)d_in[30];
  (void)in_sizes; (void)n_in; (void)out_size;

  // workspace layout (bytes)
  char* ws = (char*)d_ws;
  float*          xskip    = (float*)         (ws + 0);          // 16,777,216
  unsigned short* cat      = (unsigned short*)(ws + 16777216);   // 12,582,912
  unsigned short* wsw      = (unsigned short*)(ws + 29360128);   //    188,416
  float*          rowstats = (float*)         (ws + 29548544);   //    524,288
  float*          qkvb     = (float*)         (ws + 30072832);   //      1,152
  float*          mlpb1    = (float*)         (ws + 30073984);   //        256
  float*          part     = (float*)         (ws + 30074240);   //      4,096
  if(ws_size < 30078336u) return;

  float* out = (float*)d_out;

  kprep<<<dim3(370), dim3(256), 0, stream>>>(inW, Wq, Wk, Wv, mhW1, mhW2,
      mW1, mW2, mW3, mW4, mss, mls, msb, bq, bk, bv, mlb, mb1, wsw, qkvb, mlpb1);
  k1_patch<<<dim3(4096), dim3(256), 0, stream>>>(x, ln1s, ln1b, wsw, inb, ln2s, ln2b,
      xskip, rowstats);
  kA_attn<<<dim3(768), dim3(256), 0, stream>>>(xskip, rowstats, wsw, qkvb, cat);
  kB_tail<<<dim3(1024), dim3(256), 0, stream>>>(cat, xskip,
      wsw + 67584, mhb1, wsw + 73728, mhb2,
      wsw + 77824, mlpb1, wsw + 81920, mb2, wsw + 86016, mb3, wsw + 90112, mb4,
      outW, part);
  k5_out<<<dim3(1), dim3(256), 0, stream>>>(part, outb, out);
}